// Round 1
// baseline (3613.748 us; speedup 1.0000x reference)
//
#include <hip/hip_runtime.h>
#include <hip/hip_fp16.h>
#include <cstdint>
#include <cstddef>

typedef _Float16 f16;
typedef _Float16 f16x2 __attribute__((ext_vector_type(2)));
typedef _Float16 f16x4 __attribute__((ext_vector_type(4)));
typedef _Float16 f16x8 __attribute__((ext_vector_type(8)));
typedef float f32x4 __attribute__((ext_vector_type(4)));

#define S_LEN 2048
#define BATCH 64
#define I_DIM 128
#define H_DIM 512
#define O_DIM 64

// v_dot2_f32_f16 (fp32 accumulate — used in the small GEMMs only).
__device__ __forceinline__ float fdot2f(f16x2 a, f16x2 b, float c) {
#if __has_builtin(__builtin_amdgcn_fdot2)
    return __builtin_amdgcn_fdot2(a, b, c, false);
#else
    return c + (float)a.x * (float)b.x + (float)a.y * (float)b.y;
#endif
}

// ---------------------------------------------------------------------------
// Phase 1: u[row][c] = sum_k x[row][k] * Wih[k][c], rows = B*S, K=128, N=512.
// (unchanged from baseline)
// ---------------------------------------------------------------------------
__global__ __launch_bounds__(256)
void u_gemm_kernel(const float* __restrict__ x, const float* __restrict__ Wih,
                   f16* __restrict__ u) {
    const int tid = threadIdx.x;
    const int r0 = blockIdx.x * 32;
    const int c0 = blockIdx.y * 128;

    __shared__ __align__(16) f16x2 wih_s[I_DIM / 2][128];
    __shared__ __align__(16) f16x2 x_s[32][I_DIM / 2];

#pragma unroll
    for (int i = 0; i < 32; ++i) {
        int idx = i * 256 + tid;
        int kp = idx >> 7;
        int cl = idx & 127;
        float w0 = Wih[(size_t)(2 * kp + 0) * H_DIM + c0 + cl];
        float w1 = Wih[(size_t)(2 * kp + 1) * H_DIM + c0 + cl];
        f16x2 w; w.x = (f16)w0; w.y = (f16)w1;
        wih_s[kp][cl] = w;
    }
    const float4* xs = (const float4*)(x + (size_t)r0 * I_DIM);
    f16x4* xd = (f16x4*)x_s;
#pragma unroll
    for (int i = 0; i < 4; ++i) {
        int idx = i * 256 + tid;
        float4 v = xs[idx];
        f16x4 h; h.x = (f16)v.x; h.y = (f16)v.y; h.z = (f16)v.z; h.w = (f16)v.w;
        xd[idx] = h;
    }
    __syncthreads();

    const int cl = tid & 127;
    const int rh = tid >> 7;
    float acc[16];
#pragma unroll
    for (int r = 0; r < 16; ++r) acc[r] = 0.f;

#pragma unroll
    for (int kc = 0; kc < 2; ++kc) {
        f16x2 wv[32];
#pragma unroll
        for (int i = 0; i < 32; ++i) wv[i] = wih_s[kc * 32 + i][cl];
#pragma unroll
        for (int r = 0; r < 16; ++r) {
            const int row = rh * 16 + r;
#pragma unroll
            for (int m = 0; m < 8; ++m) {
                f16x8 h8 = *(const f16x8*)(&x_s[row][kc * 32 + 4 * m]);
                const f16x2* hp = (const f16x2*)&h8;
                acc[r] = fdot2f(wv[4 * m + 0], hp[0], acc[r]);
                acc[r] = fdot2f(wv[4 * m + 1], hp[1], acc[r]);
                acc[r] = fdot2f(wv[4 * m + 2], hp[2], acc[r]);
                acc[r] = fdot2f(wv[4 * m + 3], hp[3], acc[r]);
            }
        }
    }
#pragma unroll
    for (int r = 0; r < 16; ++r) {
        int row = r0 + rh * 16 + r;
        u[(size_t)row * H_DIM + c0 + cl] = (f16)acc[r];
    }
}

// ---------------------------------------------------------------------------
// Phase 2: scan via replicated-A MFMA. One WG (512 thr = 8 waves) per batch.
//
// z = h @ W_rec computed as v_mfma_f32_16x16x32_f16 with the A operand
// (h k-slice) replicated across all 16 rows -> every D row equals z, no
// cross-lane reduction needed, and the A-side is layout-immune. A and B are
// loaded with the SAME lane->k map (k = kt*32 + (lane>>4)*8 + j), so the dot
// product is invariant to the hardware's internal k ordering.
//
// Wave w owns output cols [w*64, w*64+64): n-tiles j=0..3, lane l holds
// D col = j*16 + (l&15) of tile j -> lane's own column is exactly tid.
// W as B-fragments: per thread 64 frags (kt=0..15, j=0..3) x 8 f16.
// kt 0..11 (48 frags = 192 VGPRs) in registers; kt 12..15 (16 frags) in LDS
// (128 KB) -> per-step LDS stream ~128 KB + broadcast A reads (~8 KB).
// One barrier/step, double-buffered h (2 x 1 KB).
// ---------------------------------------------------------------------------
#define NREG_KT 12

__global__ __launch_bounds__(512, 2)
void rnn_scan_kernel(const float* __restrict__ Wrec, f16* __restrict__ uhs) {
    const int tid = threadIdx.x;
    const int b = blockIdx.x;
    const int lane = tid & 63;
    const int w = tid >> 6;              // wave 0..7
    const int n0 = w * 64;               // this wave's 64 output columns
    const int grp = lane >> 4;           // 0..3 (16-lane group)
    const int li = lane & 15;

    __shared__ __align__(16) f16x8 wlds[16 - NREG_KT][4][512];  // 128 KB
    __shared__ __align__(16) f16 h_lds[2][H_DIM];               // 2 KB

    // ---- preload W B-fragments ----
    // frag (kt, j): lane holds W[kt*32 + grp*8 + jj][n0 + j*16 + li], jj=0..7
    f16x8 wf[NREG_KT][4];
#pragma unroll
    for (int kt = 0; kt < NREG_KT; ++kt)
#pragma unroll
        for (int j = 0; j < 4; ++j) {
            f16x8 v;
#pragma unroll
            for (int jj = 0; jj < 8; ++jj)
                v[jj] = (f16)Wrec[(size_t)(kt * 32 + grp * 8 + jj) * H_DIM +
                                  (n0 + j * 16 + li)];
            wf[kt][j] = v;
        }
#pragma unroll
    for (int kt = NREG_KT; kt < 16; ++kt)
#pragma unroll
        for (int j = 0; j < 4; ++j) {
            f16x8 v;
#pragma unroll
            for (int jj = 0; jj < 8; ++jj)
                v[jj] = (f16)Wrec[(size_t)(kt * 32 + grp * 8 + jj) * H_DIM +
                                  (n0 + j * 16 + li)];
            wlds[kt - NREG_KT][j][tid] = v;
        }
    h_lds[0][tid] = (f16)0.f;            // 512 threads cover the 512 h entries
    __syncthreads();

    // each thread owns output column c = tid: (tid>>6)*64 + (lane>>4)*16 + (lane&15) == tid
    const f16* __restrict__ u_ptr = uhs + (size_t)b * S_LEN * H_DIM + tid;
    f16* __restrict__ o_ptr = uhs + (size_t)b * S_LEN * H_DIM + tid;

    float h_prev = 0.f;
    float u_cur = (float)u_ptr[0];
    f16 u_n1 = (f16)0.f;
    if (S_LEN > 1) u_n1 = u_ptr[H_DIM];

    for (int t = 0; t < S_LEN; ++t) {
        // prefetch u two steps ahead (load->use distance ~2 steps)
        f16 u_n2 = (f16)0.f;
        if (t + 2 < S_LEN) u_n2 = u_ptr[(size_t)(t + 2) * H_DIM];

        const f16* hb = h_lds[t & 1];
        f32x4 acc0 = {0.f, 0.f, 0.f, 0.f};
        f32x4 acc1 = {0.f, 0.f, 0.f, 0.f};
        f32x4 acc2 = {0.f, 0.f, 0.f, 0.f};
        f32x4 acc3 = {0.f, 0.f, 0.f, 0.f};

#pragma unroll
        for (int kt = 0; kt < 16; ++kt) {
            // A-frag: h[kt*32 + grp*8 .. +7], same addr for all 16 lanes of a
            // group -> LDS broadcast read (4 distinct 16B addrs per wave).
            f16x8 av = *(const f16x8*)(hb + kt * 32 + grp * 8);
            f16x8 b0, b1, b2, b3;
            if (kt < NREG_KT) {
                b0 = wf[kt][0]; b1 = wf[kt][1]; b2 = wf[kt][2]; b3 = wf[kt][3];
            } else {
                b0 = wlds[kt - NREG_KT][0][tid];
                b1 = wlds[kt - NREG_KT][1][tid];
                b2 = wlds[kt - NREG_KT][2][tid];
                b3 = wlds[kt - NREG_KT][3][tid];
            }
            acc0 = __builtin_amdgcn_mfma_f32_16x16x32_f16(av, b0, acc0, 0, 0, 0);
            acc1 = __builtin_amdgcn_mfma_f32_16x16x32_f16(av, b1, acc1, 0, 0, 0);
            acc2 = __builtin_amdgcn_mfma_f32_16x16x32_f16(av, b2, acc2, 0, 0, 0);
            acc3 = __builtin_amdgcn_mfma_f32_16x16x32_f16(av, b3, acc3, 0, 0, 0);
        }

        // all D rows are replicated -> reg 0 of tile (grp) is this lane's z
        float z = grp == 0 ? acc0[0]
                : grp == 1 ? acc1[0]
                : grp == 2 ? acc2[0]
                           : acc3[0];
        z += u_cur;

        // tanh(z) = 1 - 2/(exp(2z)+1)
        float e2 = __expf(2.f * z);
        float r = 1.f - 2.f * __builtin_amdgcn_rcpf(e2 + 1.f);
        h_prev = 0.8f * h_prev + 0.2f * r;
        f16 hh = (f16)h_prev;

        h_lds[(t + 1) & 1][tid] = hh;        // next step's h (other buffer)
        o_ptr[(size_t)t * H_DIM] = hh;       // hs[b][t][tid], coalesced 2B
        u_cur = (float)u_n1;
        u_n1 = u_n2;
        __syncthreads();
    }
}

// ---------------------------------------------------------------------------
// Phase 3: out[row][o] = sum_k hs[row][k] * Who[k][o], K=512, O=64, fp32 out.
// (unchanged from baseline)
// ---------------------------------------------------------------------------
__global__ __launch_bounds__(256)
void out_gemm_kernel(const f16* __restrict__ hs, const float* __restrict__ Who,
                     float* __restrict__ out) {
    const int tid = threadIdx.x;
    const int r0 = blockIdx.x * 32;

    __shared__ __align__(16) f16x2 who_s[128][O_DIM];
    __shared__ __align__(16) f16x2 hs_s[32][128];

    const int o = tid & 63;
    const int rg = tid >> 6;

    float acc[8];
#pragma unroll
    for (int r = 0; r < 8; ++r) acc[r] = 0.f;

    for (int kc = 0; kc < 2; ++kc) {
        if (kc) __syncthreads();
#pragma unroll
        for (int i = 0; i < 32; ++i) {
            int idx = i * 256 + tid;
            int kp = idx >> 6;
            int oc = idx & 63;
            float w0 = Who[(size_t)(kc * 256 + 2 * kp + 0) * O_DIM + oc];
            float w1 = Who[(size_t)(kc * 256 + 2 * kp + 1) * O_DIM + oc];
            f16x2 w; w.x = (f16)w0; w.y = (f16)w1;
            who_s[kp][oc] = w;
        }
        f16x8* hd = (f16x8*)hs_s;
#pragma unroll
        for (int i = 0; i < 4; ++i) {
            int idx = i * 256 + tid;
            int r = idx >> 5;
            int m = idx & 31;
            f16x8 v = *(const f16x8*)(hs + (size_t)(r0 + r) * H_DIM + kc * 256 + m * 8);
            hd[idx] = v;
        }
        __syncthreads();

#pragma unroll
        for (int sc = 0; sc < 4; ++sc) {
            f16x2 wv[32];
#pragma unroll
            for (int i = 0; i < 32; ++i) wv[i] = who_s[sc * 32 + i][o];
#pragma unroll
            for (int r = 0; r < 8; ++r) {
                const int row = rg * 8 + r;
#pragma unroll
                for (int m = 0; m < 8; ++m) {
                    f16x8 h8 = *(const f16x8*)(&hs_s[row][sc * 32 + 4 * m]);
                    const f16x2* hp = (const f16x2*)&h8;
                    acc[r] = fdot2f(wv[4 * m + 0], hp[0], acc[r]);
                    acc[r] = fdot2f(wv[4 * m + 1], hp[1], acc[r]);
                    acc[r] = fdot2f(wv[4 * m + 2], hp[2], acc[r]);
                    acc[r] = fdot2f(wv[4 * m + 3], hp[3], acc[r]);
                }
            }
        }
    }
#pragma unroll
    for (int r = 0; r < 8; ++r) {
        int row = r0 + rg * 8 + r;
        out[(size_t)row * O_DIM + o] = acc[r];
    }
}

extern "C" void kernel_launch(void* const* d_in, const int* in_sizes, int n_in,
                              void* d_out, int out_size, void* d_ws, size_t ws_size,
                              hipStream_t stream) {
    const float* x    = (const float*)d_in[0];   // [64][2048][128]
    const float* Wih  = (const float*)d_in[1];   // [128][512]
    const float* Wrec = (const float*)d_in[2];   // [512][512]
    const float* Who  = (const float*)d_in[3];   // [512][64]
    float* out = (float*)d_out;                  // [64][2048][64]
    f16* uhs = (f16*)d_ws;                       // 128 MB: u, then hs in-place

    const int R = BATCH * S_LEN;

    u_gemm_kernel<<<dim3(R / 32, H_DIM / 128), 256, 0, stream>>>(x, Wih, uhs);
    rnn_scan_kernel<<<dim3(BATCH), 512, 0, stream>>>(Wrec, uhs);
    out_gemm_kernel<<<dim3(R / 32), 256, 0, stream>>>(uhs, Who, out);
}

// Round 2
// 3222.308 us; speedup vs baseline: 1.1215x; 1.1215x over previous
//
#include <hip/hip_runtime.h>
#include <hip/hip_fp16.h>
#include <cstdint>
#include <cstddef>

typedef _Float16 f16;
typedef _Float16 f16x2 __attribute__((ext_vector_type(2)));
typedef _Float16 f16x4 __attribute__((ext_vector_type(4)));
typedef _Float16 f16x8 __attribute__((ext_vector_type(8)));
typedef int i32x4 __attribute__((ext_vector_type(4)));

#define S_LEN 2048
#define BATCH 64
#define I_DIM 128
#define H_DIM 512
#define O_DIM 64

// v_dot2_f32_f16 (fp32 accumulate — used in the small GEMMs only).
__device__ __forceinline__ float fdot2f(f16x2 a, f16x2 b, float c) {
#if __has_builtin(__builtin_amdgcn_fdot2)
    return __builtin_amdgcn_fdot2(a, b, c, false);
#else
    return c + (float)a.x * (float)b.x + (float)a.y * (float)b.y;
#endif
}

// ---------------------------------------------------------------------------
// Phase 1: u[row][c] = sum_k x[row][k] * Wih[k][c], rows = B*S, K=128, N=512.
// (unchanged)
// ---------------------------------------------------------------------------
__global__ __launch_bounds__(256)
void u_gemm_kernel(const float* __restrict__ x, const float* __restrict__ Wih,
                   f16* __restrict__ u) {
    const int tid = threadIdx.x;
    const int r0 = blockIdx.x * 32;
    const int c0 = blockIdx.y * 128;

    __shared__ __align__(16) f16x2 wih_s[I_DIM / 2][128];
    __shared__ __align__(16) f16x2 x_s[32][I_DIM / 2];

#pragma unroll
    for (int i = 0; i < 32; ++i) {
        int idx = i * 256 + tid;
        int kp = idx >> 7;
        int cl = idx & 127;
        float w0 = Wih[(size_t)(2 * kp + 0) * H_DIM + c0 + cl];
        float w1 = Wih[(size_t)(2 * kp + 1) * H_DIM + c0 + cl];
        f16x2 w; w.x = (f16)w0; w.y = (f16)w1;
        wih_s[kp][cl] = w;
    }
    const float4* xs = (const float4*)(x + (size_t)r0 * I_DIM);
    f16x4* xd = (f16x4*)x_s;
#pragma unroll
    for (int i = 0; i < 4; ++i) {
        int idx = i * 256 + tid;
        float4 v = xs[idx];
        f16x4 h; h.x = (f16)v.x; h.y = (f16)v.y; h.z = (f16)v.z; h.w = (f16)v.w;
        xd[idx] = h;
    }
    __syncthreads();

    const int cl = tid & 127;
    const int rh = tid >> 7;
    float acc[16];
#pragma unroll
    for (int r = 0; r < 16; ++r) acc[r] = 0.f;

#pragma unroll
    for (int kc = 0; kc < 2; ++kc) {
        f16x2 wv[32];
#pragma unroll
        for (int i = 0; i < 32; ++i) wv[i] = wih_s[kc * 32 + i][cl];
#pragma unroll
        for (int r = 0; r < 16; ++r) {
            const int row = rh * 16 + r;
#pragma unroll
            for (int m = 0; m < 8; ++m) {
                f16x8 h8v = *(const f16x8*)(&x_s[row][kc * 32 + 4 * m]);
                const f16x2* hp = (const f16x2*)&h8v;
                acc[r] = fdot2f(wv[4 * m + 0], hp[0], acc[r]);
                acc[r] = fdot2f(wv[4 * m + 1], hp[1], acc[r]);
                acc[r] = fdot2f(wv[4 * m + 2], hp[2], acc[r]);
                acc[r] = fdot2f(wv[4 * m + 3], hp[3], acc[r]);
            }
        }
    }
#pragma unroll
    for (int r = 0; r < 16; ++r) {
        int row = r0 + rh * 16 + r;
        u[(size_t)row * H_DIM + c0 + cl] = (f16)acc[r];
    }
}

// ---------------------------------------------------------------------------
// Phase 2: scan via int8 MFMA with W fully register-resident.
//
// Why i8: W in f16 is 512 KB = the entire CU register file, forcing >=100 KB
// of LDS streaming per step (the measured bottleneck: ~256 wave-wide LDS
// instrs x 12cy ~= 3100cy/step). W in i8 = 256 KB -> 256 VGPRs/thread at
// 4 waves, fully resident; zero B-side LDS traffic.
//
// Structure: 256 threads = 4 waves (1 wave/SIMD, 512-reg budget). Wave w owns
// cols [w*128, w*128+128) = 8 j-tiles of 16. mfma_i32_16x16x64_i8, A = h (i8)
// replicated across all 16 rows (layout-immune; any HW (grp,byte)->k bijection
// cancels since A and B use the same packing). D col = lane&15 (verified,
// dtype-independent) -> lane's own cols are c0 = w*128+l and c1 = c0+64:
// z0 = acc[j=grp][0], z1 = acc[j=4+grp][0], no cross-lane reduction.
//
// Quantization: per-column scale sc_c = 127/max_k|W[k][c]| (max ~3.4sigma of
// 512 samples). Exact i32 accumulate; z = acc * (max_c/127^2). h state kept
// in f32 registers; only the matmul operand is quantized (h8 = rint(127 h)).
// Estimated added error ~0.004 rms on z per step.
//
// Per-step cost model: LDS = 8 A-reads (b128, broadcast) x 4 waves + 2 byte
// writes/thread ~= 40 instrs ~420cy (vs 3100 before); MFMA 64/wave x ~5.1cy
// = 326cy/SIMD; VALU tail ~100cy. Step ~700-900cy vs measured 3800.
// ---------------------------------------------------------------------------
__global__ __launch_bounds__(256, 1)
void rnn_scan_kernel(const float* __restrict__ Wrec, f16* __restrict__ uhs) {
    const int tid = threadIdx.x;          // 0..255
    const int b = blockIdx.x;
    const int l = tid & 63;
    const int w = tid >> 6;               // wave 0..3
    const int grp = l >> 4;               // 0..3
    const int li = l & 15;

    __shared__ __align__(16) signed char h8[2][512];   // double-buffered h (i8)

    // ---- per-column max + pack W into register-resident i8 B-fragments ----
    // frag (kt, j): lane holds W[kt*64 + grp*16 + jj][w*128 + j*16 + li],
    // jj=0..15 packed little-endian into 4 dwords (byte jj -> word jj>>2).
    i32x4 wf[8][8];   // [kt][j] = 256 VGPRs
    float rm[8];      // per-j column max (this lane's frag column)

#pragma unroll
    for (int j = 0; j < 8; ++j) {
        const int col = w * 128 + j * 16 + li;
        const float* wp = Wrec + col;
        // pass 1: column max
        float m0 = 0.f, m1 = 0.f, m2 = 0.f, m3 = 0.f;
        for (int k = 0; k < 512; k += 4) {
            m0 = fmaxf(m0, __builtin_fabsf(wp[(size_t)(k + 0) * H_DIM]));
            m1 = fmaxf(m1, __builtin_fabsf(wp[(size_t)(k + 1) * H_DIM]));
            m2 = fmaxf(m2, __builtin_fabsf(wp[(size_t)(k + 2) * H_DIM]));
            m3 = fmaxf(m3, __builtin_fabsf(wp[(size_t)(k + 3) * H_DIM]));
        }
        float m = fmaxf(fmaxf(m0, m1), fmaxf(m2, m3));
        m = fmaxf(m, 1e-20f);
        rm[j] = m;
        const float sc = 127.f / m;
        // pass 2: quantize + pack
#pragma unroll
        for (int kt = 0; kt < 8; ++kt) {
            int wd0 = 0, wd1 = 0, wd2 = 0, wd3 = 0;
#pragma unroll
            for (int jj = 0; jj < 16; ++jj) {
                float v = wp[(size_t)(kt * 64 + grp * 16 + jj) * H_DIM] * sc;
                v = fminf(fmaxf(v, -127.f), 127.f);
                int q = ((int)rintf(v)) & 255;
                int sh = 8 * (jj & 3);
                if (jj < 4)       wd0 |= q << sh;
                else if (jj < 8)  wd1 |= q << sh;
                else if (jj < 12) wd2 |= q << sh;
                else              wd3 |= q << sh;
            }
            i32x4 f; f.x = wd0; f.y = wd1; f.z = wd2; f.w = wd3;
            wf[kt][j] = f;
        }
    }

    // zero h buffer 0 (h_0 = 0)
    h8[0][tid] = 0;
    h8[0][tid + 256] = 0;

    // this thread's two output columns
    const int c0 = w * 128 + l;           // == w*128 + grp*16 + li  (j = grp)
    f16* io0 = uhs + (size_t)b * S_LEN * H_DIM + c0;
    f16* io1 = io0 + 64;                  // j = 4 + grp

    // z recompose scales: rm[grp] / 127^2 (static-index select chains —
    // runtime-indexed reads of rm[] would go to scratch, rule #20)
    float mg0 = grp == 0 ? rm[0] : grp == 1 ? rm[1] : grp == 2 ? rm[2] : rm[3];
    float mg1 = grp == 0 ? rm[4] : grp == 1 ? rm[5] : grp == 2 ? rm[6] : rm[7];
    const float inv0 = mg0 * (1.f / 16129.f);
    const float inv1 = mg1 * (1.f / 16129.f);

    float hp0 = 0.f, hp1 = 0.f;
    float uc0 = (float)io0[0], uc1 = (float)io1[0];
    f16 ua0 = (f16)0.f, ua1 = (f16)0.f;
    if (S_LEN > 1) { ua0 = io0[H_DIM]; ua1 = io1[H_DIM]; }

    __syncthreads();

    for (int t = 0; t < S_LEN; ++t) {
        // prefetch u(t+2)
        f16 ub0 = (f16)0.f, ub1 = (f16)0.f;
        if (t + 2 < S_LEN) {
            ub0 = io0[(size_t)(t + 2) * H_DIM];
            ub1 = io1[(size_t)(t + 2) * H_DIM];
        }

        const signed char* hb = h8[t & 1];
        i32x4 a0 = {0,0,0,0}, a1 = {0,0,0,0}, a2 = {0,0,0,0}, a3 = {0,0,0,0};
        i32x4 a4 = {0,0,0,0}, a5 = {0,0,0,0}, a6 = {0,0,0,0}, a7 = {0,0,0,0};

#pragma unroll
        for (int kt = 0; kt < 8; ++kt) {
            // A-frag: h8[kt*64 + grp*16 .. +15], same addr for the 16-lane
            // group -> broadcast b128, conflict-free.
            i32x4 av = *(const i32x4*)(hb + kt * 64 + grp * 16);
            a0 = __builtin_amdgcn_mfma_i32_16x16x64_i8(av, wf[kt][0], a0, 0, 0, 0);
            a1 = __builtin_amdgcn_mfma_i32_16x16x64_i8(av, wf[kt][1], a1, 0, 0, 0);
            a2 = __builtin_amdgcn_mfma_i32_16x16x64_i8(av, wf[kt][2], a2, 0, 0, 0);
            a3 = __builtin_amdgcn_mfma_i32_16x16x64_i8(av, wf[kt][3], a3, 0, 0, 0);
            a4 = __builtin_amdgcn_mfma_i32_16x16x64_i8(av, wf[kt][4], a4, 0, 0, 0);
            a5 = __builtin_amdgcn_mfma_i32_16x16x64_i8(av, wf[kt][5], a5, 0, 0, 0);
            a6 = __builtin_amdgcn_mfma_i32_16x16x64_i8(av, wf[kt][6], a6, 0, 0, 0);
            a7 = __builtin_amdgcn_mfma_i32_16x16x64_i8(av, wf[kt][7], a7, 0, 0, 0);
        }

        // replicated-A: all D rows equal -> reg 0 of tile j is this lane's z
        int zi0 = grp == 0 ? a0[0] : grp == 1 ? a1[0] : grp == 2 ? a2[0] : a3[0];
        int zi1 = grp == 0 ? a4[0] : grp == 1 ? a5[0] : grp == 2 ? a6[0] : a7[0];
        float z0 = (float)zi0 * inv0 + uc0;
        float z1 = (float)zi1 * inv1 + uc1;

        // tanh(z) = 1 - 2/(exp(2z)+1)
        float e0 = __expf(2.f * z0);
        float r0 = 1.f - 2.f * __builtin_amdgcn_rcpf(e0 + 1.f);
        float e1 = __expf(2.f * z1);
        float r1 = 1.f - 2.f * __builtin_amdgcn_rcpf(e1 + 1.f);
        hp0 = 0.8f * hp0 + 0.2f * r0;
        hp1 = 0.8f * hp1 + 0.2f * r1;

        io0[(size_t)t * H_DIM] = (f16)hp0;     // hs (f16, phase-3 input)
        io1[(size_t)t * H_DIM] = (f16)hp1;

        signed char* hn = h8[(t + 1) & 1];     // next step's A operand (i8)
        hn[c0]      = (signed char)(int)rintf(hp0 * 127.f);
        hn[c0 + 64] = (signed char)(int)rintf(hp1 * 127.f);

        uc0 = (float)ua0; uc1 = (float)ua1;
        ua0 = ub0; ua1 = ub1;
        __syncthreads();
    }
}

// ---------------------------------------------------------------------------
// Phase 3: out[row][o] = sum_k hs[row][k] * Who[k][o], K=512, O=64, fp32 out.
// (unchanged)
// ---------------------------------------------------------------------------
__global__ __launch_bounds__(256)
void out_gemm_kernel(const f16* __restrict__ hs, const float* __restrict__ Who,
                     float* __restrict__ out) {
    const int tid = threadIdx.x;
    const int r0 = blockIdx.x * 32;

    __shared__ __align__(16) f16x2 who_s[128][O_DIM];
    __shared__ __align__(16) f16x2 hs_s[32][128];

    const int o = tid & 63;
    const int rg = tid >> 6;

    float acc[8];
#pragma unroll
    for (int r = 0; r < 8; ++r) acc[r] = 0.f;

    for (int kc = 0; kc < 2; ++kc) {
        if (kc) __syncthreads();
#pragma unroll
        for (int i = 0; i < 32; ++i) {
            int idx = i * 256 + tid;
            int kp = idx >> 6;
            int oc = idx & 63;
            float w0 = Who[(size_t)(kc * 256 + 2 * kp + 0) * O_DIM + oc];
            float w1 = Who[(size_t)(kc * 256 + 2 * kp + 1) * O_DIM + oc];
            f16x2 wv2; wv2.x = (f16)w0; wv2.y = (f16)w1;
            who_s[kp][oc] = wv2;
        }
        f16x8* hd = (f16x8*)hs_s;
#pragma unroll
        for (int i = 0; i < 4; ++i) {
            int idx = i * 256 + tid;
            int r = idx >> 5;
            int m = idx & 31;
            f16x8 v = *(const f16x8*)(hs + (size_t)(r0 + r) * H_DIM + kc * 256 + m * 8);
            hd[idx] = v;
        }
        __syncthreads();

#pragma unroll
        for (int sc = 0; sc < 4; ++sc) {
            f16x2 wv[32];
#pragma unroll
            for (int i = 0; i < 32; ++i) wv[i] = who_s[sc * 32 + i][o];
#pragma unroll
            for (int r = 0; r < 8; ++r) {
                const int row = rg * 8 + r;
#pragma unroll
                for (int m = 0; m < 8; ++m) {
                    f16x8 h8v = *(const f16x8*)(&hs_s[row][sc * 32 + 4 * m]);
                    const f16x2* hp = (const f16x2*)&h8v;
                    acc[r] = fdot2f(wv[4 * m + 0], hp[0], acc[r]);
                    acc[r] = fdot2f(wv[4 * m + 1], hp[1], acc[r]);
                    acc[r] = fdot2f(wv[4 * m + 2], hp[2], acc[r]);
                    acc[r] = fdot2f(wv[4 * m + 3], hp[3], acc[r]);
                }
            }
        }
    }
#pragma unroll
    for (int r = 0; r < 8; ++r) {
        int row = r0 + rg * 8 + r;
        out[(size_t)row * O_DIM + o] = acc[r];
    }
}

extern "C" void kernel_launch(void* const* d_in, const int* in_sizes, int n_in,
                              void* d_out, int out_size, void* d_ws, size_t ws_size,
                              hipStream_t stream) {
    const float* x    = (const float*)d_in[0];   // [64][2048][128]
    const float* Wih  = (const float*)d_in[1];   // [128][512]
    const float* Wrec = (const float*)d_in[2];   // [512][512]
    const float* Who  = (const float*)d_in[3];   // [512][64]
    float* out = (float*)d_out;                  // [64][2048][64]
    f16* uhs = (f16*)d_ws;                       // 128 MB: u, then hs in-place

    const int R = BATCH * S_LEN;

    u_gemm_kernel<<<dim3(R / 32, H_DIM / 128), 256, 0, stream>>>(x, Wih, uhs);
    rnn_scan_kernel<<<dim3(BATCH), 256, 0, stream>>>(Wrec, uhs);
    out_gemm_kernel<<<dim3(R / 32), 256, 0, stream>>>(uhs, Who, out);
}

// Round 3
// 1905.074 us; speedup vs baseline: 1.8969x; 1.6914x over previous
//
#include <hip/hip_runtime.h>
#include <hip/hip_fp16.h>
#include <cstdint>
#include <cstddef>

typedef _Float16 f16;
typedef _Float16 f16x2 __attribute__((ext_vector_type(2)));
typedef _Float16 f16x4 __attribute__((ext_vector_type(4)));
typedef _Float16 f16x8 __attribute__((ext_vector_type(8)));
typedef int i32x4 __attribute__((ext_vector_type(4)));

#define S_LEN 2048
#define BATCH 64
#define I_DIM 128
#define H_DIM 512
#define O_DIM 64

// v_dot2_f32_f16 (fp32 accumulate — used in the small GEMMs only).
__device__ __forceinline__ float fdot2f(f16x2 a, f16x2 b, float c) {
#if __has_builtin(__builtin_amdgcn_fdot2)
    return __builtin_amdgcn_fdot2(a, b, c, false);
#else
    return c + (float)a.x * (float)b.x + (float)a.y * (float)b.y;
#endif
}

// ---------------------------------------------------------------------------
// Phase 1: u[row][c] = sum_k x[row][k] * Wih[k][c], rows = B*S, K=128, N=512.
// (unchanged)
// ---------------------------------------------------------------------------
__global__ __launch_bounds__(256)
void u_gemm_kernel(const float* __restrict__ x, const float* __restrict__ Wih,
                   f16* __restrict__ u) {
    const int tid = threadIdx.x;
    const int r0 = blockIdx.x * 32;
    const int c0 = blockIdx.y * 128;

    __shared__ __align__(16) f16x2 wih_s[I_DIM / 2][128];
    __shared__ __align__(16) f16x2 x_s[32][I_DIM / 2];

#pragma unroll
    for (int i = 0; i < 32; ++i) {
        int idx = i * 256 + tid;
        int kp = idx >> 7;
        int cl = idx & 127;
        float w0 = Wih[(size_t)(2 * kp + 0) * H_DIM + c0 + cl];
        float w1 = Wih[(size_t)(2 * kp + 1) * H_DIM + c0 + cl];
        f16x2 w; w.x = (f16)w0; w.y = (f16)w1;
        wih_s[kp][cl] = w;
    }
    const float4* xs = (const float4*)(x + (size_t)r0 * I_DIM);
    f16x4* xd = (f16x4*)x_s;
#pragma unroll
    for (int i = 0; i < 4; ++i) {
        int idx = i * 256 + tid;
        float4 v = xs[idx];
        f16x4 h; h.x = (f16)v.x; h.y = (f16)v.y; h.z = (f16)v.z; h.w = (f16)v.w;
        xd[idx] = h;
    }
    __syncthreads();

    const int cl = tid & 127;
    const int rh = tid >> 7;
    float acc[16];
#pragma unroll
    for (int r = 0; r < 16; ++r) acc[r] = 0.f;

#pragma unroll
    for (int kc = 0; kc < 2; ++kc) {
        f16x2 wv[32];
#pragma unroll
        for (int i = 0; i < 32; ++i) wv[i] = wih_s[kc * 32 + i][cl];
#pragma unroll
        for (int r = 0; r < 16; ++r) {
            const int row = rh * 16 + r;
#pragma unroll
            for (int m = 0; m < 8; ++m) {
                f16x8 h8v = *(const f16x8*)(&x_s[row][kc * 32 + 4 * m]);
                const f16x2* hp = (const f16x2*)&h8v;
                acc[r] = fdot2f(wv[4 * m + 0], hp[0], acc[r]);
                acc[r] = fdot2f(wv[4 * m + 1], hp[1], acc[r]);
                acc[r] = fdot2f(wv[4 * m + 2], hp[2], acc[r]);
                acc[r] = fdot2f(wv[4 * m + 3], hp[3], acc[r]);
            }
        }
    }
#pragma unroll
    for (int r = 0; r < 16; ++r) {
        int row = r0 + rh * 16 + r;
        u[(size_t)row * H_DIM + c0 + cl] = (f16)acc[r];
    }
}

// ---------------------------------------------------------------------------
// Phase 2: scan via int8 MFMA, W register-resident, 8 waves (2/SIMD).
//
// R2 post-mortem: at 4 waves (1/SIMD) the 256-reg W block + working set
// overflowed the 256 arch-VGPR file (spills) and there was no second wave
// to hide ds_read/tanh/barrier latency -> 3300cy/step vs the 1306cy MFMA
// issue floor (256 mfma/CU/step x ~5.1cy/CU; the ~5cy constant is per-CU
// shared matrix throughput, not per-SIMD).
//
// Now: 512 threads = 8 waves, 2/SIMD (256-reg budget each). Wave w owns
// cols [w*64, w*64+64) = 4 j-tiles; wf[8][4] = 128 VGPRs of W per thread;
// + 16 acc + 32 A-frags + misc ~= 210 regs -> no spills, and the second
// wave per SIMD hides the serial tail. MFMA count per CU unchanged.
//
// Replicated-A trick unchanged: A = h k-slice broadcast to all 16 rows,
// same (grp,byte)->k packing on A and B -> layout- and permutation-immune;
// D col = lane&15 (verified, dtype-independent) -> thread tid owns output
// column c = tid exactly (j = grp tile, reg 0).
//
// Quantization unchanged from R2 (passed, absmax 0.0078): per-column scale
// 127/max|W[:,c]|, exact i32 accumulate, h operand = rint(127h), h state f32.
// ---------------------------------------------------------------------------
__global__ __launch_bounds__(512, 2)
void rnn_scan_kernel(const float* __restrict__ Wrec, f16* __restrict__ uhs) {
    const int tid = threadIdx.x;          // 0..511
    const int b = blockIdx.x;
    const int l = tid & 63;
    const int w = tid >> 6;               // wave 0..7
    const int grp = l >> 4;               // 0..3
    const int li = l & 15;

    __shared__ __align__(16) signed char h8[2][512];   // double-buffered h (i8)
    __shared__ float colmax[512];

    // ---- pass 1: per-column max, coalesced (thread tid scans column tid) ----
    {
        const float* wp = Wrec + tid;
        float m0 = 0.f, m1 = 0.f, m2 = 0.f, m3 = 0.f;
        for (int k = 0; k < 512; k += 4) {
            m0 = fmaxf(m0, __builtin_fabsf(wp[(size_t)(k + 0) * H_DIM]));
            m1 = fmaxf(m1, __builtin_fabsf(wp[(size_t)(k + 1) * H_DIM]));
            m2 = fmaxf(m2, __builtin_fabsf(wp[(size_t)(k + 2) * H_DIM]));
            m3 = fmaxf(m3, __builtin_fabsf(wp[(size_t)(k + 3) * H_DIM]));
        }
        float m = fmaxf(fmaxf(m0, m1), fmaxf(m2, m3));
        colmax[tid] = fmaxf(m, 1e-20f);
    }
    h8[0][tid & 511] = 0;                 // zero h buffer 0 (512 threads cover)
    __syncthreads();

    // ---- pass 2: quantize + pack W into register B-fragments ----
    // frag (kt, j): lane holds W[kt*64 + grp*16 + jj][w*64 + j*16 + li],
    // jj=0..15 packed little-endian (byte jj -> dword jj>>2).
    i32x4 wf[8][4];   // 128 VGPRs
#pragma unroll
    for (int j = 0; j < 4; ++j) {
        const int col = w * 64 + j * 16 + li;
        const float* wp = Wrec + col;
        const float sc = 127.f / colmax[col];
#pragma unroll
        for (int kt = 0; kt < 8; ++kt) {
            int wd0 = 0, wd1 = 0, wd2 = 0, wd3 = 0;
#pragma unroll
            for (int jj = 0; jj < 16; ++jj) {
                float v = wp[(size_t)(kt * 64 + grp * 16 + jj) * H_DIM] * sc;
                v = fminf(fmaxf(v, -127.f), 127.f);
                int q = ((int)rintf(v)) & 255;
                int sh = 8 * (jj & 3);
                if (jj < 4)       wd0 |= q << sh;
                else if (jj < 8)  wd1 |= q << sh;
                else if (jj < 12) wd2 |= q << sh;
                else              wd3 |= q << sh;
            }
            i32x4 f; f.x = wd0; f.y = wd1; f.z = wd2; f.w = wd3;
            wf[kt][j] = f;
        }
    }

    // this thread's output column: c = w*64 + grp*16 + li == tid (j = grp)
    f16* io = uhs + (size_t)b * S_LEN * H_DIM + tid;
    const float inv = colmax[tid] * (1.f / 16129.f);   // colmax[c]/127^2

    float hp = 0.f;
    float uc = (float)io[0];
    f16 ua = (f16)0.f;
    if (S_LEN > 1) ua = io[H_DIM];

    __syncthreads();

    for (int t = 0; t < S_LEN; ++t) {
        // prefetch u(t+2)
        f16 ub = (f16)0.f;
        if (t + 2 < S_LEN) ub = io[(size_t)(t + 2) * H_DIM];

        const signed char* hb = h8[t & 1];
        // A-frags: h8[kt*64 + grp*16 .. +15], broadcast within 16-lane group.
        i32x4 av[8];
#pragma unroll
        for (int kt = 0; kt < 8; ++kt)
            av[kt] = *(const i32x4*)(hb + kt * 64 + grp * 16);

        i32x4 a0 = {0,0,0,0}, a1 = {0,0,0,0}, a2 = {0,0,0,0}, a3 = {0,0,0,0};
#pragma unroll
        for (int kt = 0; kt < 8; ++kt) {
            a0 = __builtin_amdgcn_mfma_i32_16x16x64_i8(av[kt], wf[kt][0], a0, 0, 0, 0);
            a1 = __builtin_amdgcn_mfma_i32_16x16x64_i8(av[kt], wf[kt][1], a1, 0, 0, 0);
            a2 = __builtin_amdgcn_mfma_i32_16x16x64_i8(av[kt], wf[kt][2], a2, 0, 0, 0);
            a3 = __builtin_amdgcn_mfma_i32_16x16x64_i8(av[kt], wf[kt][3], a3, 0, 0, 0);
        }

        // replicated-A: all D rows equal -> reg 0 of tile j=grp is lane's z
        int zi = grp == 0 ? a0[0] : grp == 1 ? a1[0] : grp == 2 ? a2[0] : a3[0];
        float z = (float)zi * inv + uc;

        // tanh(z) = 1 - 2/(exp(2z)+1)
        float e2 = __expf(2.f * z);
        float r = 1.f - 2.f * __builtin_amdgcn_rcpf(e2 + 1.f);
        hp = 0.8f * hp + 0.2f * r;

        h8[(t + 1) & 1][tid] = (signed char)(int)rintf(hp * 127.f);
        io[(size_t)t * H_DIM] = (f16)hp;      // hs (f16, phase-3 input)

        uc = (float)ua;
        ua = ub;
        __syncthreads();
    }
}

// ---------------------------------------------------------------------------
// Phase 3: out[row][o] = sum_k hs[row][k] * Who[k][o], K=512, O=64, fp32 out.
// (unchanged)
// ---------------------------------------------------------------------------
__global__ __launch_bounds__(256)
void out_gemm_kernel(const f16* __restrict__ hs, const float* __restrict__ Who,
                     float* __restrict__ out) {
    const int tid = threadIdx.x;
    const int r0 = blockIdx.x * 32;

    __shared__ __align__(16) f16x2 who_s[128][O_DIM];
    __shared__ __align__(16) f16x2 hs_s[32][128];

    const int o = tid & 63;
    const int rg = tid >> 6;

    float acc[8];
#pragma unroll
    for (int r = 0; r < 8; ++r) acc[r] = 0.f;

    for (int kc = 0; kc < 2; ++kc) {
        if (kc) __syncthreads();
#pragma unroll
        for (int i = 0; i < 32; ++i) {
            int idx = i * 256 + tid;
            int kp = idx >> 6;
            int oc = idx & 63;
            float w0 = Who[(size_t)(kc * 256 + 2 * kp + 0) * O_DIM + oc];
            float w1 = Who[(size_t)(kc * 256 + 2 * kp + 1) * O_DIM + oc];
            f16x2 wv2; wv2.x = (f16)w0; wv2.y = (f16)w1;
            who_s[kp][oc] = wv2;
        }
        f16x8* hd = (f16x8*)hs_s;
#pragma unroll
        for (int i = 0; i < 4; ++i) {
            int idx = i * 256 + tid;
            int r = idx >> 5;
            int m = idx & 31;
            f16x8 v = *(const f16x8*)(hs + (size_t)(r0 + r) * H_DIM + kc * 256 + m * 8);
            hd[idx] = v;
        }
        __syncthreads();

#pragma unroll
        for (int sc = 0; sc < 4; ++sc) {
            f16x2 wv[32];
#pragma unroll
            for (int i = 0; i < 32; ++i) wv[i] = who_s[sc * 32 + i][o];
#pragma unroll
            for (int r = 0; r < 8; ++r) {
                const int row = rg * 8 + r;
#pragma unroll
                for (int m = 0; m < 8; ++m) {
                    f16x8 h8v = *(const f16x8*)(&hs_s[row][sc * 32 + 4 * m]);
                    const f16x2* hp = (const f16x2*)&h8v;
                    acc[r] = fdot2f(wv[4 * m + 0], hp[0], acc[r]);
                    acc[r] = fdot2f(wv[4 * m + 1], hp[1], acc[r]);
                    acc[r] = fdot2f(wv[4 * m + 2], hp[2], acc[r]);
                    acc[r] = fdot2f(wv[4 * m + 3], hp[3], acc[r]);
                }
            }
        }
    }
#pragma unroll
    for (int r = 0; r < 8; ++r) {
        int row = r0 + rg * 8 + r;
        out[(size_t)row * O_DIM + o] = acc[r];
    }
}

extern "C" void kernel_launch(void* const* d_in, const int* in_sizes, int n_in,
                              void* d_out, int out_size, void* d_ws, size_t ws_size,
                              hipStream_t stream) {
    const float* x    = (const float*)d_in[0];   // [64][2048][128]
    const float* Wih  = (const float*)d_in[1];   // [128][512]
    const float* Wrec = (const float*)d_in[2];   // [512][512]
    const float* Who  = (const float*)d_in[3];   // [512][64]
    float* out = (float*)d_out;                  // [64][2048][64]
    f16* uhs = (f16*)d_ws;                       // 128 MB: u, then hs in-place

    const int R = BATCH * S_LEN;

    u_gemm_kernel<<<dim3(R / 32, H_DIM / 128), 256, 0, stream>>>(x, Wih, uhs);
    rnn_scan_kernel<<<dim3(BATCH), 512, 0, stream>>>(Wrec, uhs);
    out_gemm_kernel<<<dim3(R / 32), 256, 0, stream>>>(uhs, Who, out);
}